// Round 4
// baseline (281.360 us; speedup 1.0000x reference)
//
#include <hip/hip_runtime.h>
#include <cstddef>

#define B_ROWS 8192
#define DIM    1024
#define NSESS  32
#define MT     128       // rows per M-tile
#define NTILE  128       // cols per N-tile
#define BK     64        // k-elems per phase = 2 MFMA k-steps
#define KITERS (DIM / BK)   // 16
#define TPE    3         // m-tiles per expert
#define LROW   72        // shorts per LDS row: 64 bf16 + 8 pad = 144 B
#define TSZ    (MT * LROW)
#define NXCD   8
#define EPX    (NSESS / NXCD)        // experts per XCD = 4
#define BPE    (TPE * (DIM / NTILE)) // blocks per expert = 24

#define XB_BYTES ((size_t)B_ROWS * DIM * 2)        // 16 MiB bf16 x
#define WB_BYTES ((size_t)NSESS * DIM * DIM * 2)   // 64 MiB bf16 W

typedef __attribute__((ext_vector_type(8))) short short8;
typedef __attribute__((ext_vector_type(4))) float floatx4;
typedef __attribute__((ext_vector_type(4))) int intx4;
typedef __attribute__((ext_vector_type(2))) unsigned int uintx2;
typedef __attribute__((ext_vector_type(4))) unsigned int uintx4;

// RNE fp32->bf16 for two values, packed into one dword via v_perm_b32.
__device__ __forceinline__ unsigned pack_bf16_2(float fa, float fb) {
  unsigned a = __builtin_bit_cast(unsigned, fa);
  unsigned b = __builtin_bit_cast(unsigned, fb);
  a += 0x7fffu + ((a >> 16) & 1u);
  b += 0x7fffu + ((b >> 16) & 1u);
  return __builtin_amdgcn_perm(b, a, 0x07060302u); // low = bf16(fa), high = bf16(fb)
}

// Round-9 (post-mortem r8: occupancy 14.6->26% spill-free, time FLAT again.
// Little's law closes the books: ~40MB aggregate in-flight / 4.9TB/s service
// = 20k cy/phase = measured. Kernel time == total vector-load bytes / service
// rate; occupancy and cache blend shifts were both flat because BYTES were
// constant. Lever = fewer bytes+requests). This round:
//  - bf16 PRE-PASS into d_ws (x 16MB, W 64MB; RNE identical to old in-kernel
//    pack -> bitwise-same MFMA inputs). GEMM loads bf16: 8 loads/wave/phase
//    (was 16), 8KB in flight (was 16), zero cvt VALU, ds_write_b128 verbatim.
//  - demand 670MB -> ~330MB; x per-XCD footprint 4MB -> 2MB (fits L2 under
//    the W stream).
//  - fallback to proven r8 fp32 kernel if ws_size < 80MiB.

// ---------------- convert pass: fp32 -> bf16 (RNE), 8 floats/thread/iter ----
__global__ __launch_bounds__(256) void cvt_bf16_kernel(
    const float* __restrict__ src, unsigned short* __restrict__ dst, int n8)
{
  const int stride = gridDim.x * blockDim.x;
  for (int i = blockIdx.x * blockDim.x + threadIdx.x; i < n8; i += stride) {
    const floatx4 a = ((const floatx4*)src)[2 * i];
    const floatx4 b = ((const floatx4*)src)[2 * i + 1];
    uintx4 o = { pack_bf16_2(a[0], a[1]), pack_bf16_2(a[2], a[3]),
                 pack_bf16_2(b[0], b[1]), pack_bf16_2(b[2], b[3]) };
    *(uintx4*)(dst + (size_t)i * 8) = o;
  }
}

// ---------------- bf16 GEMM (primary path) ---------------------------------
__global__ __launch_bounds__(256, 3) void gemm_kernel_bf16(
    const unsigned short* __restrict__ xb, const unsigned short* __restrict__ wb,
    const float* __restrict__ bias, const int* __restrict__ sidx,
    float* __restrict__ out)
{
  __shared__ __align__(16) short As[TSZ], Bs[TSZ];
  __shared__ int row_ids[MT];
  __shared__ int psum[256];

  // ---- XCD-clustered decode ----
  const int hw    = blockIdx.x;          // 0..767, assumed XCD = hw % 8
  const int xcd   = hw & (NXCD - 1);
  const int r     = hw >> 3;
  const int s     = xcd * EPX + (r / BPE);
  const int rr    = r % BPE;
  const int ntile = rr / TPE;
  const int mtile = rr % TPE;
  const int tid   = threadIdx.x;

  const int lane = tid & 63;
  const int wv   = tid >> 6;
  const int wm   = wv >> 1;
  const int wn   = wv & 1;
  const int fr   = lane & 15;
  const int kg   = lane >> 4;

  // ---- staging: instr j covers tile-rows srow8 + j*8; 8 rows x 128B ----
  const int srow8 = wv * 32 + (lane >> 3);   // + j*8, j=0..3 -> rows wv*32..+31
  const int sch   = lane & 7;                // 16-B chunk within 128-B window

  // B byte-offsets + k0 B-loads issued before the sidx scan.
  unsigned boff[4];
  short8 wr[4];
  {
    const unsigned wbyte = (unsigned)s * (unsigned)(DIM * DIM * 2)
                         + (unsigned)(ntile * NTILE) * (unsigned)(DIM * 2);
#pragma unroll
    for (int j = 0; j < 4; ++j) {
      boff[j] = wbyte + (unsigned)((srow8 + j * 8) * (DIM * 2) + sch * 16);
      wr[j] = *(const short8*)((const char*)wb + boff[j]);
    }
  }

  // ---- ranked compaction: rows with sidx==s, ranks [mtile*128, +128) ----
  const intx4* sv = (const intx4*)(sidx + tid * 32);
  int c = 0;
#pragma unroll
  for (int j = 0; j < 8; ++j) {
    const intx4 v = sv[j];
#pragma unroll
    for (int e = 0; e < 4; ++e) c += (v[e] == s);
  }
  psum[tid] = c;
  __syncthreads();
#pragma unroll
  for (int d = 1; d < 256; d <<= 1) {
    const int mine = psum[tid];
    const int add  = (tid >= d) ? psum[tid - d] : 0;
    __syncthreads();
    psum[tid] = mine + add;
    __syncthreads();
  }
  const int total = psum[255];
  const int nrows = (total - mtile * MT) < 0 ? 0
                  : ((total - mtile * MT) > MT ? MT : (total - mtile * MT));
  if (nrows == 0) return;               // uniform across block
  const int base_rank = psum[tid] - c;

  if (tid < MT) row_ids[tid] = -1;
  __syncthreads();
  {
    int r2 = base_rank;
    const int lo = mtile * MT, hi = lo + MT;
#pragma unroll
    for (int j = 0; j < 8; ++j) {
      const intx4 v = sv[j];
#pragma unroll
      for (int e = 0; e < 4; ++e) {
        if (v[e] == s) {
          if (r2 >= lo && r2 < hi) row_ids[r2 - lo] = tid * 32 + 4 * j + e;
          ++r2;
        }
      }
    }
  }
  __syncthreads();

  unsigned aoff[4];
  short8 xr[4];
#pragma unroll
  for (int j = 0; j < 4; ++j) {
    int ar = row_ids[srow8 + j * 8];
    if (ar < 0) ar = 0;                 // dummy; epilogue masks rows >= nrows
    aoff[j] = (unsigned)(ar * (DIM * 2) + sch * 16);
    xr[j] = *(const short8*)((const char*)xb + aoff[j]);   // k0 A-loads
  }

  floatx4 acc[4][4] = {};

#define LOADREGS(KB)                                                           \
  {                                                                            \
    _Pragma("unroll")                                                          \
    for (int j = 0; j < 4; ++j) {                                              \
      xr[j] = *(const short8*)((const char*)xb + aoff[j] + (KB) * (BK * 2));   \
      wr[j] = *(const short8*)((const char*)wb + boff[j] + (KB) * (BK * 2));   \
    }                                                                          \
  }

#define DSWRITE()                                                              \
  {                                                                            \
    _Pragma("unroll")                                                          \
    for (int j = 0; j < 4; ++j) {                                              \
      const int off = (srow8 + j * 8) * LROW + sch * 8;                        \
      *(short8*)&As[off] = xr[j];                                              \
      *(short8*)&Bs[off] = wr[j];                                              \
    }                                                                          \
  }

#define COMPUTE()                                                              \
  {                                                                            \
    _Pragma("unroll")                                                          \
    for (int s2 = 0; s2 < 2; ++s2) {                                           \
      short8 fb[4];                                                            \
      _Pragma("unroll")                                                        \
      for (int i = 0; i < 4; ++i)                                              \
        fb[i] = *(const short8*)&Bs[(wn * 64 + i * 16 + fr) * LROW + s2 * 32 + kg * 8]; \
      _Pragma("unroll")                                                        \
      for (int mi = 0; mi < 4; ++mi) {                                         \
        const short8 fa = *(const short8*)&As[(wm * 64 + mi * 16 + fr) * LROW + s2 * 32 + kg * 8]; \
        _Pragma("unroll")                                                      \
        for (int ni = 0; ni < 4; ++ni)                                         \
          acc[mi][ni] = __builtin_amdgcn_mfma_f32_16x16x32_bf16(               \
              fa, fb[ni], acc[mi][ni], 0, 0, 0);                               \
      }                                                                        \
    }                                                                          \
  }

  // prologue: k0 already in regs -> stage into LDS
  DSWRITE();
  __syncthreads();

  for (int kb = 0; kb < KITERS; ++kb) {
    if (kb + 1 < KITERS) LOADREGS(kb + 1);   // in flight across compute+barrier
    COMPUTE();
    if (kb + 1 < KITERS) {
      __syncthreads();
      DSWRITE();                             // vmcnt wait lands here
      __syncthreads();
    }
  }

#undef LOADREGS
#undef DSWRITE
#undef COMPUTE

  // epilogue: D row = (lane>>4)*4 + reg, D col = lane&15
  const int col0 = ntile * NTILE + wn * 64;
#pragma unroll
  for (int ni = 0; ni < 4; ++ni) {
    const int n = col0 + ni * 16 + fr;
    const float bv = bias[s * DIM + n];
#pragma unroll
    for (int mi = 0; mi < 4; ++mi) {
      const int mbase = wm * 64 + mi * 16 + kg * 4;
#pragma unroll
      for (int rr2 = 0; rr2 < 4; ++rr2) {
        const int ml = mbase + rr2;
        if (ml < nrows) {
          const int orow = row_ids[ml];
          out[(size_t)orow * DIM + n] = acc[mi][ni][rr2] + bv;
        }
      }
    }
  }
}

// ---------------- fp32 fallback (proven r8 kernel) --------------------------
__global__ __launch_bounds__(256, 3) void gemm_kernel(
    const float* __restrict__ x, const float* __restrict__ W,
    const float* __restrict__ bias, const int* __restrict__ sidx,
    float* __restrict__ out)
{
  __shared__ __align__(16) short As[TSZ], Bs[TSZ];
  __shared__ int row_ids[MT];
  __shared__ int psum[256];

  const int hw    = blockIdx.x;
  const int xcd   = hw & (NXCD - 1);
  const int r     = hw >> 3;
  const int s     = xcd * EPX + (r / BPE);
  const int rr    = r % BPE;
  const int ntile = rr / TPE;
  const int mtile = rr % TPE;
  const int tid   = threadIdx.x;

  const int lane = tid & 63;
  const int wv   = tid >> 6;
  const int wm   = wv >> 1;
  const int wn   = wv & 1;
  const int fr   = lane & 15;
  const int kg   = lane >> 4;

  const int srow   = wv * 32 + (lane >> 4);
  const int schunk = lane & 15;

  unsigned boff[8];
  floatx4 wreg[8];
  {
    const unsigned wbyte =
        (unsigned)(((size_t)s * DIM * DIM + (size_t)(ntile * NTILE) * DIM) * 4u);
#pragma unroll
    for (int j = 0; j < 8; ++j) {
      const int tr = srow + j * 4;
      boff[j] = wbyte + (unsigned)((tr * DIM + schunk * 4) * 4);
      wreg[j] = *(const floatx4*)((const char*)W + boff[j]);
    }
  }

  const intx4* sv = (const intx4*)(sidx + tid * 32);
  int c = 0;
#pragma unroll
  for (int j = 0; j < 8; ++j) {
    const intx4 v = sv[j];
#pragma unroll
    for (int e = 0; e < 4; ++e) c += (v[e] == s);
  }
  psum[tid] = c;
  __syncthreads();
#pragma unroll
  for (int d = 1; d < 256; d <<= 1) {
    const int mine = psum[tid];
    const int add  = (tid >= d) ? psum[tid - d] : 0;
    __syncthreads();
    psum[tid] = mine + add;
    __syncthreads();
  }
  const int total = psum[255];
  const int nrows = (total - mtile * MT) < 0 ? 0
                  : ((total - mtile * MT) > MT ? MT : (total - mtile * MT));
  if (nrows == 0) return;
  const int base_rank = psum[tid] - c;

  if (tid < MT) row_ids[tid] = -1;
  __syncthreads();
  {
    int r2 = base_rank;
    const int lo = mtile * MT, hi = lo + MT;
#pragma unroll
    for (int j = 0; j < 8; ++j) {
      const intx4 v = sv[j];
#pragma unroll
      for (int e = 0; e < 4; ++e) {
        if (v[e] == s) {
          if (r2 >= lo && r2 < hi) row_ids[r2 - lo] = tid * 32 + 4 * j + e;
          ++r2;
        }
      }
    }
  }
  __syncthreads();

  unsigned aoff[8];
  floatx4 xreg[8];
#pragma unroll
  for (int j = 0; j < 8; ++j) {
    int ar = row_ids[srow + j * 4];
    if (ar < 0) ar = 0;
    aoff[j] = (unsigned)((ar * DIM + schunk * 4) * 4);
    xreg[j] = *(const floatx4*)((const char*)x + aoff[j]);
  }

  floatx4 acc[4][4] = {};

#define LOADREGS(KB)                                                           \
  {                                                                            \
    _Pragma("unroll")                                                          \
    for (int j = 0; j < 8; ++j) {                                              \
      xreg[j] = *(const floatx4*)((const char*)x + aoff[j] + (KB) * (BK * 4)); \
      wreg[j] = *(const floatx4*)((const char*)W + boff[j] + (KB) * (BK * 4)); \
    }                                                                          \
  }

#define CVTWRITE()                                                             \
  {                                                                            \
    _Pragma("unroll")                                                          \
    for (int j = 0; j < 8; ++j) {                                              \
      const int off = (srow + j * 4) * LROW + schunk * 4;                      \
      uintx2 ua = { pack_bf16_2(xreg[j][0], xreg[j][1]),                       \
                    pack_bf16_2(xreg[j][2], xreg[j][3]) };                     \
      uintx2 ub = { pack_bf16_2(wreg[j][0], wreg[j][1]),                       \
                    pack_bf16_2(wreg[j][2], wreg[j][3]) };                     \
      *(uintx2*)&As[off] = ua;                                                 \
      *(uintx2*)&Bs[off] = ub;                                                 \
    }                                                                          \
  }

#define COMPUTE()                                                              \
  {                                                                            \
    _Pragma("unroll")                                                          \
    for (int s2 = 0; s2 < 2; ++s2) {                                           \
      short8 fb[4];                                                            \
      _Pragma("unroll")                                                        \
      for (int i = 0; i < 4; ++i)                                              \
        fb[i] = *(const short8*)&Bs[(wn * 64 + i * 16 + fr) * LROW + s2 * 32 + kg * 8]; \
      _Pragma("unroll")                                                        \
      for (int mi = 0; mi < 4; ++mi) {                                         \
        const short8 fa = *(const short8*)&As[(wm * 64 + mi * 16 + fr) * LROW + s2 * 32 + kg * 8]; \
        _Pragma("unroll")                                                      \
        for (int ni = 0; ni < 4; ++ni)                                         \
          acc[mi][ni] = __builtin_amdgcn_mfma_f32_16x16x32_bf16(               \
              fa, fb[ni], acc[mi][ni], 0, 0, 0);                               \
      }                                                                        \
    }                                                                          \
  }

  CVTWRITE();
  __syncthreads();

  for (int kb = 0; kb < KITERS; ++kb) {
    if (kb + 1 < KITERS) LOADREGS(kb + 1);
    COMPUTE();
    if (kb + 1 < KITERS) {
      __syncthreads();
      CVTWRITE();
      __syncthreads();
    }
  }

#undef LOADREGS
#undef CVTWRITE
#undef COMPUTE

  const int col0 = ntile * NTILE + wn * 64;
#pragma unroll
  for (int ni = 0; ni < 4; ++ni) {
    const int n = col0 + ni * 16 + fr;
    const float bv = bias[s * DIM + n];
#pragma unroll
    for (int mi = 0; mi < 4; ++mi) {
      const int mbase = wm * 64 + mi * 16 + kg * 4;
#pragma unroll
      for (int rr2 = 0; rr2 < 4; ++rr2) {
        const int ml = mbase + rr2;
        if (ml < nrows) {
          const int orow = row_ids[ml];
          out[(size_t)orow * DIM + n] = acc[mi][ni][rr2] + bv;
        }
      }
    }
  }
}

extern "C" void kernel_launch(void* const* d_in, const int* in_sizes, int n_in,
                              void* d_out, int out_size, void* d_ws, size_t ws_size,
                              hipStream_t stream) {
  const float* x    = (const float*)d_in[0];
  const float* W    = (const float*)d_in[1];
  const float* b    = (const float*)d_in[2];
  const int*   sidx = (const int*)d_in[3];
  float* out = (float*)d_out;

  if (d_ws && ws_size >= XB_BYTES + WB_BYTES) {
    unsigned short* xb = (unsigned short*)d_ws;
    unsigned short* wb = xb + (size_t)B_ROWS * DIM;
    hipLaunchKernelGGL(cvt_bf16_kernel, dim3(1024), dim3(256), 0, stream,
                       x, xb, B_ROWS * DIM / 8);
    hipLaunchKernelGGL(cvt_bf16_kernel, dim3(2048), dim3(256), 0, stream,
                       W, wb, NSESS * DIM * DIM / 8);
    hipLaunchKernelGGL(gemm_kernel_bf16, dim3(NSESS * TPE * (DIM / NTILE)),
                       dim3(256), 0, stream, xb, wb, b, sidx, out);
  } else {
    hipLaunchKernelGGL(gemm_kernel, dim3(NSESS * TPE * (DIM / NTILE)),
                       dim3(256), 0, stream, x, W, b, sidx, out);
  }
}